// Round 2
// baseline (477.190 us; speedup 1.0000x reference)
//
#include <hip/hip_runtime.h>
#include <math.h>
#include <stdint.h>

// ---------------- problem dims ----------------
#define B_   32
#define I_   2048
#define J_   16
#define C_   64
#define D_   32
#define CD_  2048           // C_*D_ "columns"
#define W_CSTR (I_*D_*J_)   // 1048576 floats
#define W_ISTR (D_*J_)      // 512 floats
#define X_BSTR (I_*J_)      // 32768 floats
#define EPS_ 1e-7f

typedef _Float16 half8 __attribute__((ext_vector_type(8)));
typedef float    f32x16 __attribute__((ext_vector_type(16)));

// MFMA geometry (v_mfma_f32_32x32x16_f16), swapped orientation:
//   A = wf:  m = lane&31 (= d), k = (lane>>5)*8 + e (= j)
//   B = xf:  n = lane&31 (= b), k = (lane>>5)*8 + e (= j)
//   C/D:     col(n=b) = lane&31, row(m=d) = (r&3) + 8*(r>>2) + 4*(lane>>5)

// async global->LDS, 16B per lane; dst must be wave-uniform base (HW adds lane*16)
__device__ __forceinline__ void glds16(const void* g, void* l) {
  __builtin_amdgcn_global_load_lds(
      (const __attribute__((address_space(1))) void*)g,
      (__attribute__((address_space(3))) void*)l, 16, 0, 0);
}

// exact-tail counted waits for the depth-3 ring (k fully unrolled -> static)
#define WAITK(k) do {                                                      \
    if ((k) < 30)       asm volatile("s_waitcnt vmcnt(2)" ::: "memory");   \
    else if ((k) == 30) asm volatile("s_waitcnt vmcnt(1)" ::: "memory");   \
    else                asm volatile("s_waitcnt vmcnt(0)" ::: "memory");   \
  } while (0)

__device__ __forceinline__ half8 wfrag_from_f32(const float* __restrict__ W,
                                                int c, int i, int l) {
  const float* wp = W + (size_t)c*W_CSTR + (size_t)i*W_ISTR
                      + (size_t)(l & 31)*J_ + ((l >> 5) << 3);
  float4 a = *(const float4*)wp;
  float4 b = *(const float4*)(wp + 4);
  half8 h;
  h[0]=(_Float16)a.x; h[1]=(_Float16)a.y; h[2]=(_Float16)a.z; h[3]=(_Float16)a.w;
  h[4]=(_Float16)b.x; h[5]=(_Float16)b.y; h[6]=(_Float16)b.z; h[7]=(_Float16)b.w;
  return h;
}

// ================= K0: pack x into B-fragment layout =================
__global__ __launch_bounds__(256) void k_xpack(const float* __restrict__ x,
                                               half8* __restrict__ xh) {
  const int tg = blockIdx.x*256 + threadIdx.x;    // 0..131071
  const int i = tg >> 6, l = tg & 63;
  const int b = l & 31, jb = (l >> 5) << 3;
  const float* xp = x + (size_t)b*X_BSTR + (size_t)i*J_ + jb;
  float4 a = *(const float4*)xp;
  float4 bb = *(const float4*)(xp + 4);
  half8 h;
  h[0]=(_Float16)a.x;  h[1]=(_Float16)a.y;  h[2]=(_Float16)a.z;  h[3]=(_Float16)a.w;
  h[4]=(_Float16)bb.x; h[5]=(_Float16)bb.y; h[6]=(_Float16)bb.z; h[7]=(_Float16)bb.w;
  xh[tg] = h;
}

// ================= K0b: pure-stream W f32 -> f16 fragment pack =============
// g = tile*64 + l ; tile = c*2048 + i ; one wave handles one 2KiB tile.
__global__ __launch_bounds__(256) void k_wpack(const float* __restrict__ W,
                                               half8* __restrict__ WBv) {
  const int t0 = blockIdx.x*256 + threadIdx.x;    // 0..2M-1
  #pragma unroll
  for (int it = 0; it < 4; it++) {
    const int g = t0 + it*2097152;                // 8Mi half8 total
    const int l = g & 63;
    const size_t tile = (size_t)(g >> 6);
    const float* wp = W + tile*512 + (size_t)(l & 31)*16 + ((l >> 5) << 3);
    float4 a  = *(const float4*)wp;
    float4 bb = *(const float4*)(wp + 4);
    half8 h;
    h[0]=(_Float16)a.x;  h[1]=(_Float16)a.y;  h[2]=(_Float16)a.z;  h[3]=(_Float16)a.w;
    h[4]=(_Float16)bb.x; h[5]=(_Float16)bb.y; h[6]=(_Float16)bb.z; h[7]=(_Float16)bb.w;
    WBv[g] = h;
  }
}

// ================= K1: pass A (s0 partials), glds-ring ================
// part layout: [chunk=64][c=64][d=32][b=32] f32
template<bool USE_WB>
__global__ __launch_bounds__(512, 4) void k_mfmaA(const float* __restrict__ W,
                                                  const _Float16* __restrict__ WB,
                                                  const half8* __restrict__ xh,
                                                  float* __restrict__ part) {
  __shared__ __align__(16) char XH[32*1024];
  __shared__ __align__(16) char RING[8*3*1024];
  const int t = threadIdx.x, l = t & 63, w = t >> 6;
  const int ic = blockIdx.x, c = blockIdx.y*8 + w;
  const int b = l & 31, h4 = (l >> 5)*4;

  const char* xsrc = (const char*)xh + (size_t)ic*32*1024;
  #pragma unroll
  for (int q = 0; q < 4; q++) {
    const int k = w*4 + q;
    glds16(xsrc + (size_t)k*1024 + (size_t)l*16, XH + k*1024);
  }
  char* ring = RING + w*3*1024;
  const char* wsrc = (const char*)WB + ((size_t)c*I_ + (size_t)ic*32)*1024;
  if (USE_WB) {
    glds16(wsrc + (size_t)l*16, ring);
    glds16(wsrc + 1024 + (size_t)l*16, ring + 1024);
  }
  asm volatile("s_waitcnt vmcnt(0)" ::: "memory");
  __syncthreads();

  f32x16 acc = {};
  #pragma unroll
  for (int k = 0; k < 32; k++) {
    half8 wf;
    if (USE_WB) {
      if (k + 2 < 32)
        glds16(wsrc + (size_t)(k+2)*1024 + (size_t)l*16, ring + ((k+2)%3)*1024);
      WAITK(k);
      wf = *(const half8*)(ring + (k%3)*1024 + l*16);
    } else {
      wf = wfrag_from_f32(W, c, ic*32 + k, l);
    }
    half8 xf = *(const half8*)(XH + k*1024 + l*16);
    acc = __builtin_amdgcn_mfma_f32_32x32x16_f16(wf, xf, acc, 0, 0, 0);
  }
  #pragma unroll
  for (int r = 0; r < 16; r++) {
    const int dr = (r & 3) + 8*(r >> 2) + h4;    // = d
    part[(size_t)ic*(B_*CD_) + ((size_t)c*32 + dr)*32 + b] = acc[r];
  }
}

// ================= K2a: partial chunk reduce (full-chip) ==============
// grid 256: c = bx&63, q = bx>>6 sums 16 chunks -> red[q][c][t]
__global__ __launch_bounds__(1024) void k_red1(const float* __restrict__ part,
                                               float* __restrict__ red) {
  const int c = blockIdx.x & 63, q = blockIdx.x >> 6, t = threadIdx.x;
  float s = 0.f;
  #pragma unroll
  for (int ch = 0; ch < 16; ch++)
    s += part[(size_t)(q*16 + ch)*(B_*CD_) + c*1024 + t];
  red[((size_t)q*64 + c)*1024 + t] = s;
}

// ================= K2b: final reduce + squash =================
// TOUT=false: v1[c][d][b]; TOUT=true: out[b][c][d]
template<bool TOUT>
__global__ __launch_bounds__(1024) void k_red2(const float* __restrict__ red,
                                               float* __restrict__ outp,
                                               float scale) {
  __shared__ float SN[1024];
  const int c = blockIdx.x, t = threadIdx.x;
  const int d = t >> 5, b = t & 31;
  float s = 0.f;
  #pragma unroll
  for (int q = 0; q < 4; q++) s += red[((size_t)q*64 + c)*1024 + t];
  s *= scale;
  SN[t] = s*s;
  __syncthreads();
  #pragma unroll
  for (int st = 16; st >= 1; st >>= 1) {
    if (d < st) SN[t] += SN[t + st*32];
    __syncthreads();
  }
  const float sn = SN[b];
  const float sc = sn / ((1.f + sn) * sqrtf(sn + EPS_));
  const float val = s*sc;
  if (TOUT) outp[(size_t)b*CD_ + c*32 + d] = val;
  else      outp[(size_t)c*1024 + t] = val;
}

// ================= K3: b-logits -> b1[i][c][b], glds-ring ============
template<bool USE_WB>
__global__ __launch_bounds__(512, 4) void k_blogit2(const float* __restrict__ W,
                                                    const _Float16* __restrict__ WB,
                                                    const half8* __restrict__ xh,
                                                    const float* __restrict__ v1,
                                                    float* __restrict__ b1) {
  __shared__ __align__(16) char XH[32*1024];
  __shared__ __align__(16) char RING[8*3*1024];
  const int t = threadIdx.x, l = t & 63, w = t >> 6;
  const int ic = blockIdx.x, c = blockIdx.y*8 + w;
  const int b = l & 31, h4 = (l >> 5)*4;

  // v1 fragment preload (i-independent) — before the prologue drain so the
  // loads are pinned outside the counted-vmcnt loop.
  float v1r[16];
  #pragma unroll
  for (int r = 0; r < 16; r++) {
    const int dr = (r & 3) + 8*(r >> 2) + h4;
    v1r[r] = v1[(size_t)c*1024 + dr*32 + b];
  }

  const char* xsrc = (const char*)xh + (size_t)ic*32*1024;
  #pragma unroll
  for (int q = 0; q < 4; q++) {
    const int k = w*4 + q;
    glds16(xsrc + (size_t)k*1024 + (size_t)l*16, XH + k*1024);
  }
  char* ring = RING + w*3*1024;
  const char* wsrc = (const char*)WB + ((size_t)c*I_ + (size_t)ic*32)*1024;
  if (USE_WB) {
    glds16(wsrc + (size_t)l*16, ring);
    glds16(wsrc + 1024 + (size_t)l*16, ring + 1024);
  }
  asm volatile("s_waitcnt vmcnt(0)" ::: "memory");
  __syncthreads();

  float yv[32];
  #pragma unroll
  for (int k = 0; k < 32; k++) {
    half8 wf;
    if (USE_WB) {
      if (k + 2 < 32)
        glds16(wsrc + (size_t)(k+2)*1024 + (size_t)l*16, ring + ((k+2)%3)*1024);
      WAITK(k);
      wf = *(const half8*)(ring + (k%3)*1024 + l*16);
    } else {
      wf = wfrag_from_f32(W, c, ic*32 + k, l);
    }
    half8 xf = *(const half8*)(XH + k*1024 + l*16);
    f32x16 z = {};
    f32x16 u = __builtin_amdgcn_mfma_f32_32x32x16_f16(wf, xf, z, 0, 0, 0);
    float y = 0.f;
    #pragma unroll
    for (int r = 0; r < 16; r++) y += u[r]*v1r[r];  // this lane's 16 d's
    y += __shfl_xor(y, 32);                         // + other half's 16 d's
    yv[k] = y;
  }
  if (l < 32) {
    #pragma unroll
    for (int k = 0; k < 32; k++)
      b1[((size_t)(ic*32 + k)*64 + c)*32 + b] = yv[k];
  }
}

// ================= K4: softmax over c, [i][c][b] tiles =================
__global__ __launch_bounds__(256) void k_softmaxT(const float* __restrict__ b1,
                                                  float* __restrict__ c2) {
  __shared__ float ST[2048];
  __shared__ float PM[256], PS[256];
  const int i = blockIdx.x, t = threadIdx.x;
  const float* src = b1 + (size_t)i*2048;
  *(float4*)(ST + t*8)     = *(const float4*)(src + t*8);
  *(float4*)(ST + t*8 + 4) = *(const float4*)(src + t*8 + 4);
  __syncthreads();
  const int b = t & 31, ck = t >> 5;
  float m = -1e30f;
  #pragma unroll
  for (int cc = 0; cc < 8; cc++) m = fmaxf(m, ST[(ck*8 + cc)*32 + b]);
  PM[t] = m;
  __syncthreads();
  #pragma unroll
  for (int k = 0; k < 8; k++) m = fmaxf(m, PM[k*32 + b]);
  float s = 0.f;
  #pragma unroll
  for (int cc = 0; cc < 8; cc++) {
    const int idx = (ck*8 + cc)*32 + b;
    const float e = __expf(ST[idx] - m);
    s += e;
    ST[idx] = e;
  }
  PS[t] = s;
  __syncthreads();
  s = 0.f;
  #pragma unroll
  for (int k = 0; k < 8; k++) s += PS[k*32 + b];
  const float inv = 1.f / s;
  float* dst = c2 + (size_t)i*2048;
  #pragma unroll
  for (int cc = 0; cc < 8; cc++) {
    const int idx = (ck*8 + cc)*32 + b;
    dst[idx] = ST[idx] * inv;
  }
}

// ================= K5: pass B2 (s2 partials), glds-ring ==============
template<bool USE_WB>
__global__ __launch_bounds__(512, 4) void k_mfmaB2(const float* __restrict__ W,
                                                   const _Float16* __restrict__ WB,
                                                   const half8* __restrict__ xh,
                                                   const float* __restrict__ c2,
                                                   float* __restrict__ part) {
  __shared__ __align__(16) char XH[32*1024];
  __shared__ __align__(16) char RING[8*3*1024];
  const int t = threadIdx.x, l = t & 63, w = t >> 6;
  const int ic = blockIdx.x, c = blockIdx.y*8 + w;
  const int b = l & 31, h4 = (l >> 5)*4;

  // routing-weight preload (one f32 per k) — pinned before the drain.
  float cv[32];
  #pragma unroll
  for (int k = 0; k < 32; k++)
    cv[k] = c2[((size_t)(ic*32 + k)*64 + c)*32 + b];

  const char* xsrc = (const char*)xh + (size_t)ic*32*1024;
  #pragma unroll
  for (int q = 0; q < 4; q++) {
    const int k = w*4 + q;
    glds16(xsrc + (size_t)k*1024 + (size_t)l*16, XH + k*1024);
  }
  char* ring = RING + w*3*1024;
  const char* wsrc = (const char*)WB + ((size_t)c*I_ + (size_t)ic*32)*1024;
  if (USE_WB) {
    glds16(wsrc + (size_t)l*16, ring);
    glds16(wsrc + 1024 + (size_t)l*16, ring + 1024);
  }
  asm volatile("s_waitcnt vmcnt(0)" ::: "memory");
  __syncthreads();

  f32x16 s2 = {};
  #pragma unroll
  for (int k = 0; k < 32; k++) {
    half8 wf;
    if (USE_WB) {
      if (k + 2 < 32)
        glds16(wsrc + (size_t)(k+2)*1024 + (size_t)l*16, ring + ((k+2)%3)*1024);
      WAITK(k);
      wf = *(const half8*)(ring + (k%3)*1024 + l*16);
    } else {
      wf = wfrag_from_f32(W, c, ic*32 + k, l);
    }
    half8 xf = *(const half8*)(XH + k*1024 + l*16);
    f32x16 z = {};
    f32x16 u = __builtin_amdgcn_mfma_f32_32x32x16_f16(wf, xf, z, 0, 0, 0);
    #pragma unroll
    for (int r = 0; r < 16; r++) s2[r] += cv[k]*u[r];
  }
  #pragma unroll
  for (int r = 0; r < 16; r++) {
    const int dr = (r & 3) + 8*(r >> 2) + h4;
    part[(size_t)ic*(B_*CD_) + ((size_t)c*32 + dr)*32 + b] = s2[r];
  }
}

// ================= host =================
extern "C" void kernel_launch(void* const* d_in, const int* in_sizes, int n_in,
                              void* d_out, int out_size, void* d_ws, size_t ws_size,
                              hipStream_t stream) {
  (void)in_sizes; (void)n_in; (void)out_size;
  const float* x = (const float*)d_in[0];   // [32, 2048, 16] f32
  const float* W = (const float*)d_in[1];   // [64, 2048, 32, 16] f32
  float* out = (float*)d_out;               // [32, 64, 32] f32

  const size_t MiB = 1024*1024;
  char* ws = (char*)d_ws;
  const bool big = ws_size >= 164*MiB;

  _Float16* WB; float *part, *b1, *c2, *xhp, *v1, *red;
  if (big) {
    WB    = (_Float16*)(ws);                //   128 MiB f16 W fragments
    part  = (float*)(ws + 128*MiB);         //    16 MiB
    b1    = part;                           //    alias (sequential lifetime)
    c2    = (float*)(ws + 144*MiB);         //    16 MiB
    xhp   = (float*)(ws + 160*MiB);         //     2 MiB
    v1    = (float*)(ws + 162*MiB);         //   256 KiB
    red   = (float*)(ws + 163*MiB);         //     1 MiB
  } else {
    WB    = nullptr;
    part  = (float*)(ws);
    b1    = part;
    c2    = (float*)(ws + 16*MiB);
    xhp   = (float*)(ws + 32*MiB);
    v1    = (float*)(ws + 34*MiB);
    red   = (float*)(ws + 35*MiB);
  }
  half8* xh = (half8*)xhp;

  k_xpack<<<512, 256, 0, stream>>>(x, xh);
  if (big) {
    k_wpack<<<8192, 256, 0, stream>>>(W, (half8*)WB);
    k_mfmaA<true ><<<dim3(64, 8), 512, 0, stream>>>(W, WB, xh, part);
  } else {
    k_mfmaA<false><<<dim3(64, 8), 512, 0, stream>>>(W, WB, xh, part);
  }
  k_red1<<<256, 1024, 0, stream>>>(part, red);
  k_red2<false><<<64, 1024, 0, stream>>>(red, v1, 1.f/64.f);   // v1[c][d][b]
  if (big) k_blogit2<true ><<<dim3(64, 8), 512, 0, stream>>>(W, WB, xh, v1, b1);
  else     k_blogit2<false><<<dim3(64, 8), 512, 0, stream>>>(W, WB, xh, v1, b1);
  k_softmaxT<<<2048, 256, 0, stream>>>(b1, c2);
  if (big) k_mfmaB2<true ><<<dim3(64, 8), 512, 0, stream>>>(W, WB, xh, c2, part);
  else     k_mfmaB2<false><<<dim3(64, 8), 512, 0, stream>>>(W, WB, xh, c2, part);
  k_red1<<<256, 1024, 0, stream>>>(part, red);
  k_red2<true><<<64, 1024, 0, stream>>>(red, out, 1.f);
}

// Round 3
// 470.889 us; speedup vs baseline: 1.0134x; 1.0134x over previous
//
#include <hip/hip_runtime.h>
#include <math.h>
#include <stdint.h>

// ---------------- problem dims ----------------
#define B_   32
#define I_   2048
#define J_   16
#define C_   64
#define D_   32
#define CD_  2048           // C_*D_ "columns"
#define W_CSTR (I_*D_*J_)   // 1048576 floats
#define W_ISTR (D_*J_)      // 512 floats
#define X_BSTR (I_*J_)      // 32768 floats
#define EPS_ 1e-7f

typedef _Float16 half8 __attribute__((ext_vector_type(8)));
typedef float    f32x16 __attribute__((ext_vector_type(16)));

// MFMA geometry (v_mfma_f32_32x32x16_f16), swapped orientation:
//   A = wf:  m = lane&31 (= d), k = (lane>>5)*8 + e (= j)
//   B = xf:  n = lane&31 (= b), k = (lane>>5)*8 + e (= j)
//   C/D:     col(n=b) = lane&31, row(m=d) = (r&3) + 8*(r>>2) + 4*(lane>>5)
//
// Perf model (R0-R2 measured): every kernel runs at ~HBM peak (6.7 TB/s);
// dur = sum(traffic)/6.7TB/s + ~340us fixed (harness poison fills).
// => optimize TOTAL BYTES, nothing else.

__device__ __forceinline__ half8 wfrag_from_f32(const float* __restrict__ W,
                                                int c, int i, int l) {
  const float* wp = W + (size_t)c*W_CSTR + (size_t)i*W_ISTR
                      + (size_t)(l & 31)*J_ + ((l >> 5) << 3);
  float4 a = *(const float4*)wp;
  float4 b = *(const float4*)(wp + 4);
  half8 h;
  h[0]=(_Float16)a.x; h[1]=(_Float16)a.y; h[2]=(_Float16)a.z; h[3]=(_Float16)a.w;
  h[4]=(_Float16)b.x; h[5]=(_Float16)b.y; h[6]=(_Float16)b.z; h[7]=(_Float16)b.w;
  return h;
}

// ================= K0: pack x into B-fragment layout =================
__global__ __launch_bounds__(256) void k_xpack(const float* __restrict__ x,
                                               half8* __restrict__ xh) {
  const int tg = blockIdx.x*256 + threadIdx.x;    // 0..131071
  const int i = tg >> 6, l = tg & 63;
  const int b = l & 31, jb = (l >> 5) << 3;
  const float* xp = x + (size_t)b*X_BSTR + (size_t)i*J_ + jb;
  float4 a = *(const float4*)xp;
  float4 bb = *(const float4*)(xp + 4);
  half8 h;
  h[0]=(_Float16)a.x;  h[1]=(_Float16)a.y;  h[2]=(_Float16)a.z;  h[3]=(_Float16)a.w;
  h[4]=(_Float16)bb.x; h[5]=(_Float16)bb.y; h[6]=(_Float16)bb.z; h[7]=(_Float16)bb.w;
  xh[tg] = h;
}

// ================= K1: pass A (s0 partials + WB build, fused) ==========
// part layout: [chunk=64][c=64][d=32][b=32] f32
template<bool WRITE_WB>
__global__ __launch_bounds__(512, 4) void k_passA(const float* __restrict__ W,
                                                  const half8* __restrict__ xh,
                                                  float* __restrict__ part,
                                                  _Float16* __restrict__ WB) {
  const int t = threadIdx.x, l = t & 63, w = t >> 6;
  const int ic = blockIdx.x, c = blockIdx.y*8 + w;
  const int b = l & 31, h4 = (l >> 5)*4;
  f32x16 acc = {};
  #pragma unroll 4
  for (int ii = 0; ii < 32; ii++) {
    const int i = ic*32 + ii;
    half8 wf = wfrag_from_f32(W, c, i, l);
    half8 xf = xh[(size_t)i*64 + l];
    if (WRITE_WB)
      *(half8*)(WB + ((size_t)c*I_ + i)*512 + (size_t)l*8) = wf;
    acc = __builtin_amdgcn_mfma_f32_32x32x16_f16(wf, xf, acc, 0, 0, 0);
  }
  #pragma unroll
  for (int r = 0; r < 16; r++) {
    const int dr = (r & 3) + 8*(r >> 2) + h4;    // = d
    part[(size_t)ic*(B_*CD_) + ((size_t)c*32 + dr)*32 + b] = acc[r];
  }
}

// ================= K2a: partial chunk reduce (full-chip) ==============
// grid 256: c = bx&63, q = bx>>6 sums 16 chunks -> red[q][c][t]
__global__ __launch_bounds__(1024) void k_red1(const float* __restrict__ part,
                                               float* __restrict__ red) {
  const int c = blockIdx.x & 63, q = blockIdx.x >> 6, t = threadIdx.x;
  float s = 0.f;
  #pragma unroll
  for (int ch = 0; ch < 16; ch++)
    s += part[(size_t)(q*16 + ch)*(B_*CD_) + c*1024 + t];
  red[((size_t)q*64 + c)*1024 + t] = s;
}

// ================= K2b: final reduce + squash =================
// TOUT=false: v1[c][d][b]; TOUT=true: out[b][c][d]
template<bool TOUT>
__global__ __launch_bounds__(1024) void k_red2(const float* __restrict__ red,
                                               float* __restrict__ outp,
                                               float scale) {
  __shared__ float SN[1024];
  const int c = blockIdx.x, t = threadIdx.x;
  const int d = t >> 5, b = t & 31;
  float s = 0.f;
  #pragma unroll
  for (int q = 0; q < 4; q++) s += red[((size_t)q*64 + c)*1024 + t];
  s *= scale;
  SN[t] = s*s;
  __syncthreads();
  #pragma unroll
  for (int st = 16; st >= 1; st >>= 1) {
    if (d < st) SN[t] += SN[t + st*32];
    __syncthreads();
  }
  const float sn = SN[b];
  const float sc = sn / ((1.f + sn) * sqrtf(sn + EPS_));
  const float val = s*sc;
  if (TOUT) outp[(size_t)b*CD_ + c*32 + d] = val;
  else      outp[(size_t)c*1024 + t] = val;
}

// ================= K3: fused b-logits + softmax -> c2[i][c][b] =========
// Block owns 8 i's x ALL 64 c's (softmax over c is local to (b,i)).
// Eliminates the b1 global round-trip (32 MiB) and one launch.
// Wave w handles c = cc*8+w for cc=0..7; y -> LDS[8i][64c][32b] (64 KiB);
// in-block softmax; coalesced c2 write.
template<bool USE_WB>
__global__ __launch_bounds__(512, 4) void k_blogitF(const float* __restrict__ W,
                                                    const _Float16* __restrict__ WB,
                                                    const half8* __restrict__ xh,
                                                    const float* __restrict__ v1,
                                                    float* __restrict__ c2) {
  __shared__ float Y[8][64][32];                  // 64 KiB
  const int t = threadIdx.x, l = t & 63, w = t >> 6;
  const int i0 = blockIdx.x*8;
  const int b = l & 31, h4 = (l >> 5)*4;

  half8 xf[8];                                    // x fragments, reused 8x
  #pragma unroll
  for (int ii = 0; ii < 8; ii++) xf[ii] = xh[(size_t)(i0 + ii)*64 + l];

  #pragma unroll 1
  for (int cc = 0; cc < 8; cc++) {
    const int c = cc*8 + w;
    float v1r[16];                                // v1[c][d(r)][b]
    #pragma unroll
    for (int r = 0; r < 16; r++) {
      const int dr = (r & 3) + 8*(r >> 2) + h4;
      v1r[r] = v1[(size_t)c*1024 + dr*32 + b];
    }
    #pragma unroll
    for (int ii = 0; ii < 8; ii++) {
      half8 wf = USE_WB
        ? *(const half8*)(WB + ((size_t)c*I_ + i0 + ii)*512 + (size_t)l*8)
        : wfrag_from_f32(W, c, i0 + ii, l);
      f32x16 z = {};
      f32x16 u = __builtin_amdgcn_mfma_f32_32x32x16_f16(wf, xf[ii], z, 0, 0, 0);
      float y = 0.f;
      #pragma unroll
      for (int r = 0; r < 16; r++) y += u[r]*v1r[r];  // this lane's 16 d's
      y += __shfl_xor(y, 32);                         // + other half's 16
      if (l < 32) Y[ii][c][b] = y;
    }
  }
  __syncthreads();

  // softmax over c per (ii,b) row; bank = b per lane -> conflict-free
  if (t < 256) {
    const int ii = t >> 5, bb = t & 31;
    float m = -1e30f;
    #pragma unroll
    for (int c = 0; c < 64; c++) m = fmaxf(m, Y[ii][c][bb]);
    float s = 0.f;
    #pragma unroll
    for (int c = 0; c < 64; c++) {
      const float e = __expf(Y[ii][c][bb] - m);
      s += e;
      Y[ii][c][bb] = e;
    }
    const float inv = 1.f / s;
    #pragma unroll
    for (int c = 0; c < 64; c++) Y[ii][c][bb] *= inv;
  }
  __syncthreads();

  // c2 write: [i][c][b] is exactly Y's linear layout; 16384 floats/block
  float4* dst = (float4*)(c2 + (size_t)i0*2048);
  const float4* srcv = (const float4*)&Y[0][0][0];
  #pragma unroll
  for (int q = 0; q < 8; q++) dst[q*512 + t] = srcv[q*512 + t];
}

// ================= K5: pass B2 (s2 partials) =================
template<bool USE_WB>
__global__ __launch_bounds__(512, 4) void k_passB2(const float* __restrict__ W,
                                                   const _Float16* __restrict__ WB,
                                                   const half8* __restrict__ xh,
                                                   const float* __restrict__ c2,
                                                   float* __restrict__ part) {
  const int t = threadIdx.x, l = t & 63, w = t >> 6;
  const int ic = blockIdx.x, c = blockIdx.y*8 + w;
  const int b = l & 31, h4 = (l >> 5)*4;
  f32x16 s2 = {};
  #pragma unroll 4
  for (int ii = 0; ii < 32; ii++) {
    const int i = ic*32 + ii;
    half8 wf = USE_WB ? *(const half8*)(WB + ((size_t)c*I_ + i)*512 + (size_t)l*8)
                      : wfrag_from_f32(W, c, i, l);
    half8 xf = xh[(size_t)i*64 + l];
    f32x16 z = {};
    f32x16 u = __builtin_amdgcn_mfma_f32_32x32x16_f16(wf, xf, z, 0, 0, 0);
    const float cv = c2[((size_t)i*64 + c)*32 + b];
    #pragma unroll
    for (int r = 0; r < 16; r++) s2[r] += cv*u[r];
  }
  #pragma unroll
  for (int r = 0; r < 16; r++) {
    const int dr = (r & 3) + 8*(r >> 2) + h4;
    part[(size_t)ic*(B_*CD_) + ((size_t)c*32 + dr)*32 + b] = s2[r];
  }
}

// ================= host =================
extern "C" void kernel_launch(void* const* d_in, const int* in_sizes, int n_in,
                              void* d_out, int out_size, void* d_ws, size_t ws_size,
                              hipStream_t stream) {
  (void)in_sizes; (void)n_in; (void)out_size;
  const float* x = (const float*)d_in[0];   // [32, 2048, 16] f32
  const float* W = (const float*)d_in[1];   // [64, 2048, 32, 16] f32
  float* out = (float*)d_out;               // [32, 64, 32] f32

  const size_t MiB = 1024*1024;
  char* ws = (char*)d_ws;
  const bool big = ws_size >= 164*MiB;

  _Float16* WB; float *part, *c2, *xhp, *v1, *red;
  if (big) {
    WB    = (_Float16*)(ws);                //   128 MiB f16 W fragments
    part  = (float*)(ws + 128*MiB);         //    16 MiB
    c2    = (float*)(ws + 144*MiB);         //    16 MiB
    xhp   = (float*)(ws + 160*MiB);         //     2 MiB
    v1    = (float*)(ws + 162*MiB);         //   256 KiB
    red   = (float*)(ws + 163*MiB);         //     1 MiB
  } else {
    WB    = nullptr;
    part  = (float*)(ws);
    c2    = (float*)(ws + 16*MiB);
    xhp   = (float*)(ws + 32*MiB);
    v1    = (float*)(ws + 34*MiB);
    red   = (float*)(ws + 35*MiB);
  }
  half8* xh = (half8*)xhp;

  k_xpack<<<512, 256, 0, stream>>>(x, xh);
  if (big) k_passA<true ><<<dim3(64, 8), 512, 0, stream>>>(W, xh, part, WB);
  else     k_passA<false><<<dim3(64, 8), 512, 0, stream>>>(W, xh, part, WB);
  k_red1<<<256, 1024, 0, stream>>>(part, red);
  k_red2<false><<<64, 1024, 0, stream>>>(red, v1, 1.f/64.f);   // v1[c][d][b]
  if (big) k_blogitF<true ><<<256, 512, 0, stream>>>(W, WB, xh, v1, c2);
  else     k_blogitF<false><<<256, 512, 0, stream>>>(W, WB, xh, v1, c2);
  if (big) k_passB2<true ><<<dim3(64, 8), 512, 0, stream>>>(W, WB, xh, c2, part);
  else     k_passB2<false><<<dim3(64, 8), 512, 0, stream>>>(W, WB, xh, c2, part);
  k_red1<<<256, 1024, 0, stream>>>(part, red);
  k_red2<true><<<64, 1024, 0, stream>>>(red, out, 1.f);
}

// Round 5
// 454.229 us; speedup vs baseline: 1.0505x; 1.0367x over previous
//
#include <hip/hip_runtime.h>
#include <math.h>
#include <stdint.h>

// ---------------- problem dims ----------------
#define B_   32
#define I_   2048
#define J_   16
#define C_   64
#define D_   32
#define CD_  2048           // C_*D_ "columns"
#define W_CSTR (I_*D_*J_)   // 1048576 floats
#define W_ISTR (D_*J_)      // 512 floats
#define X_BSTR (I_*J_)      // 32768 floats
#define EPS_ 1e-7f

typedef _Float16 half8 __attribute__((ext_vector_type(8)));
typedef float    f32x16 __attribute__((ext_vector_type(16)));

// MFMA geometry (v_mfma_f32_32x32x16_f16), swapped orientation:
//   A = wf:  m = lane&31 (= d), k = (lane>>5)*8 + e (= j)
//   B = xf:  n = lane&31 (= b), k = (lane>>5)*8 + e (= j)
//   C/D:     col(n=b) = lane&31, row(m=d) = (r&3) + 8*(r>>2) + 4*(lane>>5)
//
// Perf model (R0-R3 measured): kernels hit ~6.7 TB/s ONLY at >=512 blocks
// (2 blocks/CU, 16 waves/CU); at 256 blocks the FMA-dot kernels fall to
// ~2.9 TB/s (R3 blogitF). dur = sum(traffic)/6.7TB/s + ~340us fixed fills.
// => optimize TOTAL BYTES, keep every kernel at grid >= 512.

__device__ __forceinline__ half8 wfrag_from_f32(const float* __restrict__ W,
                                                int c, int i, int l) {
  const float* wp = W + (size_t)c*W_CSTR + (size_t)i*W_ISTR
                      + (size_t)(l & 31)*J_ + ((l >> 5) << 3);
  float4 a = *(const float4*)wp;
  float4 b = *(const float4*)(wp + 4);
  half8 h;
  h[0]=(_Float16)a.x; h[1]=(_Float16)a.y; h[2]=(_Float16)a.z; h[3]=(_Float16)a.w;
  h[4]=(_Float16)b.x; h[5]=(_Float16)b.y; h[6]=(_Float16)b.z; h[7]=(_Float16)b.w;
  return h;
}

// ================= K0: pack x into B-fragment layout =================
__global__ __launch_bounds__(256) void k_xpack(const float* __restrict__ x,
                                               half8* __restrict__ xh) {
  const int tg = blockIdx.x*256 + threadIdx.x;    // 0..131071
  const int i = tg >> 6, l = tg & 63;
  const int b = l & 31, jb = (l >> 5) << 3;
  const float* xp = x + (size_t)b*X_BSTR + (size_t)i*J_ + jb;
  float4 a = *(const float4*)xp;
  float4 bb = *(const float4*)(xp + 4);
  half8 h;
  h[0]=(_Float16)a.x;  h[1]=(_Float16)a.y;  h[2]=(_Float16)a.z;  h[3]=(_Float16)a.w;
  h[4]=(_Float16)bb.x; h[5]=(_Float16)bb.y; h[6]=(_Float16)bb.z; h[7]=(_Float16)bb.w;
  xh[tg] = h;
}

// ================= K1: pass A (s0 partials + WB build, fused) ==========
// part layout: [chunk=64][c=64][d=32][b=32] f32
template<bool WRITE_WB>
__global__ __launch_bounds__(512, 4) void k_passA(const float* __restrict__ W,
                                                  const half8* __restrict__ xh,
                                                  float* __restrict__ part,
                                                  _Float16* __restrict__ WB) {
  const int t = threadIdx.x, l = t & 63, w = t >> 6;
  const int ic = blockIdx.x, c = blockIdx.y*8 + w;
  const int b = l & 31, h4 = (l >> 5)*4;
  f32x16 acc = {};
  #pragma unroll 4
  for (int ii = 0; ii < 32; ii++) {
    const int i = ic*32 + ii;
    half8 wf = wfrag_from_f32(W, c, i, l);
    half8 xf = xh[(size_t)i*64 + l];
    if (WRITE_WB)
      *(half8*)(WB + ((size_t)c*I_ + i)*512 + (size_t)l*8) = wf;
    acc = __builtin_amdgcn_mfma_f32_32x32x16_f16(wf, xf, acc, 0, 0, 0);
  }
  #pragma unroll
  for (int r = 0; r < 16; r++) {
    const int dr = (r & 3) + 8*(r >> 2) + h4;    // = d
    part[(size_t)ic*(B_*CD_) + ((size_t)c*32 + dr)*32 + b] = acc[r];
  }
}

// ================= K2a: partial chunk reduce (full-chip) ==============
// grid 256: c = bx&63, q = bx>>6 sums 16 chunks -> red[q][c][t]
__global__ __launch_bounds__(1024) void k_red1(const float* __restrict__ part,
                                               float* __restrict__ red) {
  const int c = blockIdx.x & 63, q = blockIdx.x >> 6, t = threadIdx.x;
  float s = 0.f;
  #pragma unroll
  for (int ch = 0; ch < 16; ch++)
    s += part[(size_t)(q*16 + ch)*(B_*CD_) + c*1024 + t];
  red[((size_t)q*64 + c)*1024 + t] = s;
}

// ================= K2b: final reduce + squash =================
// TOUT=false: v1[c][d][b]; TOUT=true: out[b][c][d]
template<bool TOUT>
__global__ __launch_bounds__(1024) void k_red2(const float* __restrict__ red,
                                               float* __restrict__ outp,
                                               float scale) {
  __shared__ float SN[1024];
  const int c = blockIdx.x, t = threadIdx.x;
  const int d = t >> 5, b = t & 31;
  float s = 0.f;
  #pragma unroll
  for (int q = 0; q < 4; q++) s += red[((size_t)q*64 + c)*1024 + t];
  s *= scale;
  SN[t] = s*s;
  __syncthreads();
  #pragma unroll
  for (int st = 16; st >= 1; st >>= 1) {
    if (d < st) SN[t] += SN[t + st*32];
    __syncthreads();
  }
  const float sn = SN[b];
  const float sc = sn / ((1.f + sn) * sqrtf(sn + EPS_));
  const float val = s*sc;
  if (TOUT) outp[(size_t)b*CD_ + c*32 + d] = val;
  else      outp[(size_t)c*1024 + t] = val;
}

// ================= K3: fused b-logits + softmax -> c2[i][c][b] =========
// Block owns 4 i's x ALL 64 c's (softmax over c is local to (b,i)).
// grid 512 (2 blocks/CU, 16 waves/CU — required for BW peak, see R3).
// Wave w handles c = cc*8+w for cc=0..7; y -> LDS[4i][64c][32b] (32 KiB);
// in-block softmax; coalesced c2 write. Kills the b1 round-trip (-32 MiB).
template<bool USE_WB>
__global__ __launch_bounds__(512, 4) void k_blogitF(const float* __restrict__ W,
                                                    const _Float16* __restrict__ WB,
                                                    const half8* __restrict__ xh,
                                                    const float* __restrict__ v1,
                                                    float* __restrict__ c2) {
  __shared__ float Y[4][64][32];                  // 32 KiB
  const int t = threadIdx.x, l = t & 63, w = t >> 6;
  const int i0 = blockIdx.x*4;
  const int b = l & 31, h4 = (l >> 5)*4;

  half8 xf[4];                                    // x fragments, reused 8x
  #pragma unroll
  for (int ii = 0; ii < 4; ii++) xf[ii] = xh[(size_t)(i0 + ii)*64 + l];

  #pragma unroll 2
  for (int cc = 0; cc < 8; cc++) {
    const int c = cc*8 + w;
    float v1r[16];                                // v1[c][d(r)][b]
    #pragma unroll
    for (int r = 0; r < 16; r++) {
      const int dr = (r & 3) + 8*(r >> 2) + h4;
      v1r[r] = v1[(size_t)c*1024 + dr*32 + b];
    }
    #pragma unroll
    for (int ii = 0; ii < 4; ii++) {
      half8 wf = USE_WB
        ? *(const half8*)(WB + ((size_t)c*I_ + i0 + ii)*512 + (size_t)l*8)
        : wfrag_from_f32(W, c, i0 + ii, l);
      f32x16 z = {};
      f32x16 u = __builtin_amdgcn_mfma_f32_32x32x16_f16(wf, xf[ii], z, 0, 0, 0);
      float y = 0.f;
      #pragma unroll
      for (int r = 0; r < 16; r++) y += u[r]*v1r[r];  // this lane's 16 d's
      y += __shfl_xor(y, 32);                         // + other half's 16
      if (l < 32) Y[ii][c][b] = y;
    }
  }
  __syncthreads();

  // softmax over c per (ii,b) row; 256 active threads, each owns 32 c's;
  // pair (t, t^1) combines via shfl_xor(1). 2-way LDS aliasing = free.
  if (t < 256) {
    const int ii = t >> 6, bb = (t >> 1) & 31, hf = (t & 1)*32;
    float m = -1e30f;
    #pragma unroll
    for (int c = 0; c < 32; c++) m = fmaxf(m, Y[ii][hf + c][bb]);
    m = fmaxf(m, __shfl_xor(m, 1));
    float s = 0.f;
    #pragma unroll
    for (int c = 0; c < 32; c++) {
      const float e = __expf(Y[ii][hf + c][bb] - m);
      s += e;
      Y[ii][hf + c][bb] = e;
    }
    s += __shfl_xor(s, 1);
    const float inv = 1.f / s;
    #pragma unroll
    for (int c = 0; c < 32; c++) Y[ii][hf + c][bb] *= inv;
  }
  __syncthreads();

  // c2 write: [i][c][b] is exactly Y's linear layout; 8192 floats/block
  float4* dst = (float4*)(c2 + (size_t)i0*2048);
  const float4* srcv = (const float4*)&Y[0][0][0];
  #pragma unroll
  for (int q = 0; q < 4; q++) dst[q*512 + t] = srcv[q*512 + t];
}

// ================= K5: pass B2 (s2 partials) =================
template<bool USE_WB>
__global__ __launch_bounds__(512, 4) void k_passB2(const float* __restrict__ W,
                                                   const _Float16* __restrict__ WB,
                                                   const half8* __restrict__ xh,
                                                   const float* __restrict__ c2,
                                                   float* __restrict__ part) {
  const int t = threadIdx.x, l = t & 63, w = t >> 6;
  const int ic = blockIdx.x, c = blockIdx.y*8 + w;
  const int b = l & 31, h4 = (l >> 5)*4;
  f32x16 s2 = {};
  #pragma unroll 4
  for (int ii = 0; ii < 32; ii++) {
    const int i = ic*32 + ii;
    half8 wf = USE_WB ? *(const half8*)(WB + ((size_t)c*I_ + i)*512 + (size_t)l*8)
                      : wfrag_from_f32(W, c, i, l);
    half8 xf = xh[(size_t)i*64 + l];
    f32x16 z = {};
    f32x16 u = __builtin_amdgcn_mfma_f32_32x32x16_f16(wf, xf, z, 0, 0, 0);
    const float cv = c2[((size_t)i*64 + c)*32 + b];
    #pragma unroll
    for (int r = 0; r < 16; r++) s2[r] += cv*u[r];
  }
  #pragma unroll
  for (int r = 0; r < 16; r++) {
    const int dr = (r & 3) + 8*(r >> 2) + h4;
    part[(size_t)ic*(B_*CD_) + ((size_t)c*32 + dr)*32 + b] = s2[r];
  }
}

// ================= host =================
extern "C" void kernel_launch(void* const* d_in, const int* in_sizes, int n_in,
                              void* d_out, int out_size, void* d_ws, size_t ws_size,
                              hipStream_t stream) {
  (void)in_sizes; (void)n_in; (void)out_size;
  const float* x = (const float*)d_in[0];   // [32, 2048, 16] f32
  const float* W = (const float*)d_in[1];   // [64, 2048, 32, 16] f32
  float* out = (float*)d_out;               // [32, 64, 32] f32

  const size_t MiB = 1024*1024;
  char* ws = (char*)d_ws;
  const bool big = ws_size >= 164*MiB;

  _Float16* WB; float *part, *c2, *xhp, *v1, *red;
  if (big) {
    WB    = (_Float16*)(ws);                //   128 MiB f16 W fragments
    part  = (float*)(ws + 128*MiB);         //    16 MiB
    c2    = (float*)(ws + 144*MiB);         //    16 MiB
    xhp   = (float*)(ws + 160*MiB);         //     2 MiB
    v1    = (float*)(ws + 162*MiB);         //   256 KiB
    red   = (float*)(ws + 163*MiB);         //     1 MiB
  } else {
    WB    = nullptr;
    part  = (float*)(ws);
    c2    = (float*)(ws + 16*MiB);
    xhp   = (float*)(ws + 32*MiB);
    v1    = (float*)(ws + 34*MiB);
    red   = (float*)(ws + 35*MiB);
  }
  half8* xh = (half8*)xhp;

  k_xpack<<<512, 256, 0, stream>>>(x, xh);
  if (big) k_passA<true ><<<dim3(64, 8), 512, 0, stream>>>(W, xh, part, WB);
  else     k_passA<false><<<dim3(64, 8), 512, 0, stream>>>(W, xh, part, WB);
  k_red1<<<256, 1024, 0, stream>>>(part, red);
  k_red2<false><<<64, 1024, 0, stream>>>(red, v1, 1.f/64.f);   // v1[c][d][b]
  if (big) k_blogitF<true ><<<512, 512, 0, stream>>>(W, WB, xh, v1, c2);
  else     k_blogitF<false><<<512, 512, 0, stream>>>(W, WB, xh, v1, c2);
  if (big) k_passB2<true ><<<dim3(64, 8), 512, 0, stream>>>(W, WB, xh, c2, part);
  else     k_passB2<false><<<dim3(64, 8), 512, 0, stream>>>(W, WB, xh, c2, part);
  k_red1<<<256, 1024, 0, stream>>>(part, red);
  k_red2<true><<<64, 1024, 0, stream>>>(red, out, 1.f);
}